// Round 13
// baseline (81.228 us; speedup 1.0000x reference)
//
#include <hip/hip_runtime.h>

#define NDIM 31
#define NPIX (256 * 256)
#define CG_FULL 3           // full CG iterations
                            // + 1 final partial iteration (phi term only)

__device__ __forceinline__ float rcpf(float x) { return __builtin_amdgcn_rcpf(x); }

// DPP-shuffled copy (VALU pipe). 0xB1=xor1, 0x4E=xor2, 0x1B=xor3(quad),
// 0x141=row_half_mirror(xor7 in 8), 0x124=row_ror:4, 0x128=row_ror:8(xor8 in 16)
template <int CTRL>
__device__ __forceinline__ float dppf(float v) {
    return __int_as_float(__builtin_amdgcn_update_dpp(
        0, __float_as_int(v), CTRL, 0xF, 0xF, true));
}
// xor16 within each 32-lane group (DS pipe)
__device__ __forceinline__ float swz16(float v) {
    return __int_as_float(__builtin_amdgcn_ds_swizzle(__float_as_int(v), 0x401F));
}

// ---- float2 = two independent pixels per thread (ILP pair) ----
__device__ __forceinline__ float2 mk2(float a, float b) { return make_float2(a, b); }
template <int CTRL>
__device__ __forceinline__ float2 dppf2(float2 v) {
    return mk2(dppf<CTRL>(v.x), dppf<CTRL>(v.y));
}
__device__ __forceinline__ float2 xor4f2(float2 v) {
    return dppf2<0x1B>(dppf2<0x141>(v));
}
__device__ __forceinline__ float2 swz16_2(float2 v) {
    return mk2(swz16(v.x), swz16(v.y));
}
// broadcast lane 0 of each 32-lane half (bbase = half-base byte address)
__device__ __forceinline__ float2 bperm0_2(float2 v, int bbase) {
    return mk2(
        __int_as_float(__builtin_amdgcn_ds_bpermute(bbase, __float_as_int(v.x))),
        __int_as_float(__builtin_amdgcn_ds_bpermute(bbase, __float_as_int(v.y))));
}
__device__ __forceinline__ float2 add2(float2 a, float2 b) { return mk2(a.x + b.x, a.y + b.y); }
__device__ __forceinline__ float2 sub2(float2 a, float2 b) { return mk2(a.x - b.x, a.y - b.y); }
__device__ __forceinline__ float2 mul2(float2 a, float2 b) { return mk2(a.x * b.x, a.y * b.y); }
__device__ __forceinline__ float2 smul2(float s, float2 a) { return mk2(s * a.x, s * a.y); }
__device__ __forceinline__ float2 fma2(float2 a, float2 b, float2 c) {
    return mk2(fmaf(a.x, b.x, c.x), fmaf(a.y, b.y, c.y));
}
__device__ __forceinline__ float2 sfma2(float s, float2 b, float2 c) {
    return mk2(fmaf(s, b.x, c.x), fmaf(s, b.y, c.y));
}
__device__ __forceinline__ float2 rcp2(float2 a) { return mk2(rcpf(a.x), rcpf(a.y)); }
__device__ __forceinline__ float2 maxe2(float2 a) {
    return mk2(fmaxf(a.x, 1e-30f), fmaxf(a.y, 1e-30f));
}

struct Sgn { float s1, s2, s4, s8, s16; };

// 32-point WHT per half, two pixels at once; chain depth = one pixel's
__device__ __forceinline__ float2 wht32_2(float2 v, const Sgn& g) {
    v = sfma2(g.s1,  v, dppf2<0xB1>(v));
    v = sfma2(g.s2,  v, dppf2<0x4E>(v));
    v = sfma2(g.s4,  v, xor4f2(v));
    v = sfma2(g.s8,  v, dppf2<0x128>(v));
    v = sfma2(g.s16, v, swz16_2(v));
    return v;
}

// sum over each 32-lane half, result in every lane
__device__ __forceinline__ float2 sum32_2(float2 s) {
    s = add2(s, dppf2<0xB1>(s));    // xor1
    s = add2(s, dppf2<0x4E>(s));    // xor2
    s = add2(s, dppf2<0x124>(s));   // ror4 within 16
    s = add2(s, dppf2<0x128>(s));   // ror8 within 16
    s = add2(s, swz16_2(s));        // xor16
    return s;
}

__global__ __launch_bounds__(256) void solver_kernel(
    const float* __restrict__ xg, const float* __restrict__ kg,
    const float* __restrict__ tg, float* __restrict__ out)
{
    const int tid = blockIdx.x * 256 + threadIdx.x;
    const int half = tid >> 5;                // each 32-lane half: 2 pixels
    const int pix0 = half * 2;
    const int lane = threadIdx.x & 63;
    const int l = lane & 31;                  // element = l-1; lane0 = WHT pad
    const int bbase = (lane & 32) << 2;

    const float t = tg[0];

    float2 x = mk2(1.0f, 1.0f), k = mk2(0.0f, 0.0f);
    if (l >= 1) {
        const int base = pix0 * NDIM + (l - 1);
        x.x = xg[base];         k.x = kg[base];
        x.y = xg[base + NDIM];  k.y = kg[base + NDIM];
    }

    Sgn g;
    g.s1  = (l & 1)  ? -1.0f : 1.0f;
    g.s2  = (l & 2)  ? -1.0f : 1.0f;
    g.s4  = (l & 4)  ? -1.0f : 1.0f;
    g.s8  = (l & 8)  ? -1.0f : 1.0f;
    g.s16 = (l & 16) ? -1.0f : 1.0f;

    // rate = S x via WHT: rate[e] = 0.5*(xh0 - xh[e+1]) at lane e+1
    float2 xt = (l >= 1) ? x : mk2(0.0f, 0.0f);
    float2 xh = wht32_2(xt, g);
    float2 xh0 = bperm0_2(xh, bbase);
    float2 rate = smul2(0.5f, sub2(xh0, xh));
    float2 inv_rate = (l == 0) ? mk2(0.0f, 0.0f) : rcp2(rate);

    // v: J = -(S^T v) - 1/x ;  w: Hessian weights
    float2 v = add2(smul2(t, sub2(mul2(k, inv_rate), mk2(1.0f, 1.0f))), inv_rate);
    if (l == 0) v = mk2(0.0f, 0.0f);
    float2 w = mul2(sfma2(t, k, mk2(1.0f, 1.0f)), mul2(inv_rate, inv_rate));

    // b = J (zero at lane 0)
    float2 vh = wht32_2(v, g);
    float2 vh0 = bperm0_2(vh, bbase);
    float2 invx = rcp2(x);
    float2 invx2 = mul2(invx, invx);
    float2 b = sub2(smul2(-0.5f, sub2(vh0, vh)), invx);
    if (l == 0) b = mk2(0.0f, 0.0f);

    // Jacobi diag: diag(H) = (S^T w) + 1/x^2  (S binary => S_ai^2 = S_ai)
    float2 wh = wht32_2(w, g);
    float2 wh0 = bperm0_2(wh, bbase);
    float2 dH = add2(smul2(0.5f, sub2(wh0, wh)), invx2);
    float2 Minv = (l == 0) ? mk2(0.0f, 0.0f) : rcp2(dH);

    const float2 w4 = smul2(0.25f, w);  // folds both WHT 0.5-scales

    // ---- PCG on H y = b; phi = b^T y = sum alpha_i * (r_i.z_i) ----
    float2 r = b;
    float2 z = mul2(Minv, r);
    float2 p = z;
    float2 rz = sum32_2(mul2(r, z));
    float2 phi = mk2(0.0f, 0.0f);

#pragma unroll
    for (int it = 0; it < CG_FULL; ++it) {
        // Ap = S^T ( w * (S p) ) + invx2 * p   (lane0 stays 0 automatically)
        float2 ph = wht32_2(p, g);
        float2 ph0 = bperm0_2(ph, bbase);
        float2 q = mul2(w4, sub2(ph0, ph));
        float2 qh = wht32_2(q, g);
        float2 qh0 = bperm0_2(qh, bbase);
        float2 Ap = fma2(invx2, p, sub2(qh0, qh));

        float2 pAp = sum32_2(mul2(p, Ap));
        float2 alpha = mul2(rz, rcp2(maxe2(pAp)));   // clamp: no inf -> no NaN
        phi = fma2(alpha, rz, phi);
        r = fma2(smul2(-1.0f, alpha), Ap, r);
        z = mul2(Minv, r);
        float2 rzn = sum32_2(mul2(r, z));
        float2 beta = mul2(rzn, rcp2(maxe2(rz)));
        rz = rzn;
        p = fma2(beta, p, z);
    }
    {   // final partial iteration: only the phi increment is observable
        float2 ph = wht32_2(p, g);
        float2 ph0 = bperm0_2(ph, bbase);
        float2 q = mul2(w4, sub2(ph0, ph));
        float2 qh = wht32_2(q, g);
        float2 qh0 = bperm0_2(qh, bbase);
        float2 Ap = fma2(invx2, p, sub2(qh0, qh));
        float2 pAp = sum32_2(mul2(p, Ap));
        float2 alpha = mul2(rz, rcp2(maxe2(pAp)));
        phi = fma2(alpha, rz, phi);
    }

    if (l == 0)
        *reinterpret_cast<float2*>(&out[pix0]) = phi;  // pix0 even -> 8B aligned
}

extern "C" void kernel_launch(void* const* d_in, const int* in_sizes, int n_in,
                              void* d_out, int out_size, void* d_ws, size_t ws_size,
                              hipStream_t stream) {
    const float* xg = (const float*)d_in[0];  // time_points
    const float* kg = (const float*)d_in[1];  // pixels
    // d_in[2] = S — Sylvester S-matrix, structure known analytically, unused
    const float* tg = (const float*)d_in[3];  // t scalar
    float* out = (float*)d_out;

    const int threads = 256;                  // 4 waves; 2 px/half => 16 px/block
    const int blocks = (NPIX * 16) / threads; // 4096
    solver_kernel<<<blocks, threads, 0, stream>>>(xg, kg, tg, out);
}